// Round 1
// baseline (582.097 us; speedup 1.0000x reference)
//
#include <hip/hip_runtime.h>
#include <hip/hip_bf16.h>
#include <stdint.h>

#define HH 768
#define WW 768
#define NN 200000
#define CI 256
#define CB 64

typedef __attribute__((ext_vector_type(8))) __bf16 bf16x8;
typedef __attribute__((ext_vector_type(4))) float f32x4;
typedef __attribute__((ext_vector_type(4))) unsigned short u16x4;

__device__ inline unsigned short f2bf(float f) {
    union { float f; unsigned int i; } v; v.f = f;
    unsigned int r = v.i + 0x7FFF + ((v.i >> 16) & 1);
    return (unsigned short)(r >> 16);
}
__device__ inline f32x4 mfma16(bf16x8 a, bf16x8 b, f32x4 c) {
    return __builtin_amdgcn_mfma_f32_16x16x32_bf16(a, b, c, 0, 0, 0);
}
__device__ inline bf16x8 ldfrag(const unsigned short* p) {
    return *(const bf16x8*)p;
}
__device__ inline bf16x8 ldfrag_f32(const float* p) {
    float4 f0 = *(const float4*)(p);
    float4 f1 = *(const float4*)(p + 4);
    bf16x8 a;
    a[0] = (__bf16)f0.x; a[1] = (__bf16)f0.y; a[2] = (__bf16)f0.z; a[3] = (__bf16)f0.w;
    a[4] = (__bf16)f1.x; a[5] = (__bf16)f1.y; a[6] = (__bf16)f1.z; a[7] = (__bf16)f1.w;
    return a;
}

// ---------------- prep kernels ----------------

__global__ void k_scatter(const int* __restrict__ coords, int* __restrict__ idx_map) {
    int i = blockIdx.x * 256 + threadIdx.x;
    if (i < NN) idx_map[coords[i]] = i;
}

__global__ void k_prepw(const float* __restrict__ w1,
                        const float* __restrict__ w2,
                        const float* __restrict__ w3,
                        unsigned short* __restrict__ w1t,
                        unsigned short* __restrict__ w2t,
                        unsigned short* __restrict__ w3t) {
    int tid = blockIdx.x * 256 + threadIdx.x;
    int stride = gridDim.x * 256;
    for (int i = tid; i < CI * CB; i += stride) {      // w1 [256][64] -> w1t [64][256]
        int k = i / CB, n = i % CB;
        w1t[n * CI + k] = f2bf(w1[i]);
    }
    for (int i = tid; i < 9 * CB * CB; i += stride) {  // w2 [9][64][64] -> per-tap [n][k]
        int t = i / (CB * CB), rem = i % (CB * CB);
        int k = rem / CB, n = rem % CB;
        w2t[t * CB * CB + n * CB + k] = f2bf(w2[i]);
    }
    for (int i = tid; i < CB * CI; i += stride) {      // w3 [64][256] -> w3t [256][64]
        int k = i / CI, n = i % CI;
        w3t[n * CB + k] = f2bf(w3[i]);
    }
}

// ---------------- stage 1: out1 = relu((feats @ w1)*s1 + b1), N x 64 ----------------
// Swapped-operand MFMA: acc lane holds [row = lane&15][4 consecutive cols = quad*4..].
// Wave tile = 32 rows x 64 cols (acc 2x4 = 32 VGPR) -> launch_bounds(256,4) = 16 waves/CU.

__global__ __launch_bounds__(256, 4) void k_gemm1(const float* __restrict__ feats,
                                                  const unsigned short* __restrict__ w1t,
                                                  const float* __restrict__ s1,
                                                  const float* __restrict__ b1,
                                                  unsigned short* __restrict__ out1) {
    const int wave = threadIdx.x >> 6;
    const int lane = threadIdx.x & 63;
    const int m = lane & 15;
    const int quad = lane >> 4;
    const int row0 = blockIdx.x * 128 + wave * 32;
    if (row0 >= NN) return;

    f32x4 acc[2][4];   // [rt][ct]
#pragma unroll
    for (int rt = 0; rt < 2; ++rt)
#pragma unroll
        for (int ct = 0; ct < 4; ++ct) acc[rt][ct] = (f32x4){0.f, 0.f, 0.f, 0.f};

#pragma unroll
    for (int ks = 0; ks < 8; ++ks) {
        bf16x8 f[2];
#pragma unroll
        for (int rt = 0; rt < 2; ++rt)
            f[rt] = ldfrag_f32(feats + (size_t)(row0 + rt * 16 + m) * CI + quad * 8 + ks * 32);
#pragma unroll
        for (int ct = 0; ct < 4; ++ct) {
            bf16x8 b = ldfrag(w1t + (ct * 16 + m) * CI + quad * 8 + ks * 32);
#pragma unroll
            for (int rt = 0; rt < 2; ++rt)
                acc[rt][ct] = mfma16(b, f[rt], acc[rt][ct]);   // swapped: computes C^T frag
        }
    }

#pragma unroll
    for (int rt = 0; rt < 2; ++rt)
#pragma unroll
        for (int ct = 0; ct < 4; ++ct) {
            int row = row0 + rt * 16 + m;
            int c0 = ct * 16 + quad * 4;
            float4 sc = *(const float4*)(s1 + c0);
            float4 bi = *(const float4*)(b1 + c0);
            float v0 = acc[rt][ct][0] * sc.x + bi.x;
            float v1 = acc[rt][ct][1] * sc.y + bi.y;
            float v2 = acc[rt][ct][2] * sc.z + bi.z;
            float v3 = acc[rt][ct][3] * sc.w + bi.w;
            u16x4 o;
            o.x = f2bf(v0 > 0.f ? v0 : 0.f);
            o.y = f2bf(v1 > 0.f ? v1 : 0.f);
            o.z = f2bf(v2 > 0.f ? v2 : 0.f);
            o.w = f2bf(v3 > 0.f ? v3 : 0.f);
            *(u16x4*)(out1 + (size_t)row * CB + c0) = o;
        }
}

// ---------------- stage 2: gathered 3x3 conv + bn2 + relu ----------------
// block = 128 rows; wave = 32 rows (2 m-tiles) x full N=64; nbr idx staged in LDS;
// branchless gather via zero-row pointer select; swapped-operand MFMA epilogue.

__global__ __launch_bounds__(256, 4) void k_conv(const unsigned short* __restrict__ out1,
                                                 const unsigned short* __restrict__ w2t,
                                                 const int* __restrict__ coords,
                                                 const int* __restrict__ idx_map,
                                                 const float* __restrict__ s2,
                                                 const float* __restrict__ b2,
                                                 const unsigned short* __restrict__ zrow,
                                                 unsigned short* __restrict__ out2) {
    __shared__ int s_nbr[128 * 9];
    const int tid = threadIdx.x;
    if (tid < 128) {
        int grow = blockIdx.x * 128 + tid;
        if (grow < NN) {
            int c = coords[grow];
            int y = c / WW, x = c - y * WW;
#pragma unroll
            for (int t = 0; t < 9; ++t) {
                int dy = t / 3 - 1, dx = t % 3 - 1;
                int ny = y + dy, nx = x + dx;
                int r = -1;
                if (ny >= 0 && ny < HH && nx >= 0 && nx < WW) r = idx_map[ny * WW + nx];
                s_nbr[tid * 9 + t] = r;
            }
        } else {
#pragma unroll
            for (int t = 0; t < 9; ++t) s_nbr[tid * 9 + t] = -1;
        }
    }
    __syncthreads();

    const int wave = tid >> 6;
    const int lane = tid & 63;
    const int m = lane & 15;
    const int quad = lane >> 4;
    const int row0 = blockIdx.x * 128 + wave * 32;
    if (row0 >= NN) return;

    f32x4 acc[2][4];   // [rt][ct]
#pragma unroll
    for (int rt = 0; rt < 2; ++rt)
#pragma unroll
        for (int ct = 0; ct < 4; ++ct) acc[rt][ct] = (f32x4){0.f, 0.f, 0.f, 0.f};

#pragma unroll
    for (int t = 0; t < 9; ++t) {
        bf16x8 a[2][2];
#pragma unroll
        for (int rt = 0; rt < 2; ++rt) {
            int r = s_nbr[(wave * 32 + rt * 16 + m) * 9 + t];
            const unsigned short* base = (r >= 0) ? (out1 + (size_t)r * CB) : zrow;
            a[rt][0] = ldfrag(base + quad * 8);
            a[rt][1] = ldfrag(base + quad * 8 + 32);
        }
#pragma unroll
        for (int ks = 0; ks < 2; ++ks)
#pragma unroll
            for (int ct = 0; ct < 4; ++ct) {
                bf16x8 b = ldfrag(w2t + t * CB * CB + (ct * 16 + m) * CB + quad * 8 + ks * 32);
#pragma unroll
                for (int rt = 0; rt < 2; ++rt)
                    acc[rt][ct] = mfma16(b, a[rt][ks], acc[rt][ct]);
            }
    }

#pragma unroll
    for (int rt = 0; rt < 2; ++rt)
#pragma unroll
        for (int ct = 0; ct < 4; ++ct) {
            int row = row0 + rt * 16 + m;
            int c0 = ct * 16 + quad * 4;
            float4 sc = *(const float4*)(s2 + c0);
            float4 bi = *(const float4*)(b2 + c0);
            float v0 = acc[rt][ct][0] * sc.x + bi.x;
            float v1 = acc[rt][ct][1] * sc.y + bi.y;
            float v2 = acc[rt][ct][2] * sc.z + bi.z;
            float v3 = acc[rt][ct][3] * sc.w + bi.w;
            u16x4 o;
            o.x = f2bf(v0 > 0.f ? v0 : 0.f);
            o.y = f2bf(v1 > 0.f ? v1 : 0.f);
            o.z = f2bf(v2 > 0.f ? v2 : 0.f);
            o.w = f2bf(v3 > 0.f ? v3 : 0.f);
            *(u16x4*)(out2 + (size_t)row * CB + c0) = o;
        }
}

// ---------------- stage 3: out = relu((out2 @ w3)*s3 + b3 + feats), N x 256 ----------------
// block = 128 rows (4 waves x 32 rows); each wave walks all 256 cols in 4 chunks of 64,
// reusing a 2x4 accumulator. Swapped layout -> float4 feats read + float4 out store.

__global__ __launch_bounds__(256, 4) void k_gemm3(const unsigned short* __restrict__ out2,
                                                  const unsigned short* __restrict__ w3t,
                                                  const float* __restrict__ s3,
                                                  const float* __restrict__ b3,
                                                  const float* __restrict__ feats,
                                                  float* __restrict__ out) {
    const int wave = threadIdx.x >> 6;
    const int lane = threadIdx.x & 63;
    const int m = lane & 15;
    const int quad = lane >> 4;
    const int row0 = blockIdx.x * 128 + wave * 32;
    if (row0 >= NN) return;

    bf16x8 arow[2][2];
#pragma unroll
    for (int rt = 0; rt < 2; ++rt) {
        const unsigned short* ap = out2 + (size_t)(row0 + rt * 16 + m) * CB + quad * 8;
        arow[rt][0] = ldfrag(ap);
        arow[rt][1] = ldfrag(ap + 32);
    }

#pragma unroll
    for (int cc = 0; cc < 4; ++cc) {
        const int cbase = cc * 64;
        f32x4 acc[2][4];   // [rt][ct]
#pragma unroll
        for (int rt = 0; rt < 2; ++rt)
#pragma unroll
            for (int ct = 0; ct < 4; ++ct) acc[rt][ct] = (f32x4){0.f, 0.f, 0.f, 0.f};

#pragma unroll
        for (int ks = 0; ks < 2; ++ks)
#pragma unroll
            for (int ct = 0; ct < 4; ++ct) {
                bf16x8 b = ldfrag(w3t + (cbase + ct * 16 + m) * CB + quad * 8 + ks * 32);
#pragma unroll
                for (int rt = 0; rt < 2; ++rt)
                    acc[rt][ct] = mfma16(b, arow[rt][ks], acc[rt][ct]);
            }

#pragma unroll
        for (int rt = 0; rt < 2; ++rt)
#pragma unroll
            for (int ct = 0; ct < 4; ++ct) {
                int row = row0 + rt * 16 + m;
                int c0 = cbase + ct * 16 + quad * 4;
                float4 sc = *(const float4*)(s3 + c0);
                float4 bi = *(const float4*)(b3 + c0);
                float4 fr = *(const float4*)(feats + (size_t)row * CI + c0);
                float4 v;
                v.x = acc[rt][ct][0] * sc.x + bi.x + fr.x;
                v.y = acc[rt][ct][1] * sc.y + bi.y + fr.y;
                v.z = acc[rt][ct][2] * sc.z + bi.z + fr.z;
                v.w = acc[rt][ct][3] * sc.w + bi.w + fr.w;
                v.x = v.x > 0.f ? v.x : 0.f;
                v.y = v.y > 0.f ? v.y : 0.f;
                v.z = v.z > 0.f ? v.z : 0.f;
                v.w = v.w > 0.f ? v.w : 0.f;
                *(float4*)(out + (size_t)row * CI + c0) = v;
            }
    }
}

// ---------------- launch ----------------

extern "C" void kernel_launch(void* const* d_in, const int* in_sizes, int n_in,
                              void* d_out, int out_size, void* d_ws, size_t ws_size,
                              hipStream_t stream) {
    const float* feats = (const float*)d_in[0];
    const int* coords = (const int*)d_in[1];
    const float* w1 = (const float*)d_in[2];
    const float* w2 = (const float*)d_in[3];
    const float* w3 = (const float*)d_in[4];
    const float* s1 = (const float*)d_in[5];
    const float* b1 = (const float*)d_in[6];
    const float* s2 = (const float*)d_in[7];
    const float* b2 = (const float*)d_in[8];
    const float* s3 = (const float*)d_in[9];
    const float* b3 = (const float*)d_in[10];
    float* out = (float*)d_out;

    char* ws = (char*)d_ws;
    int* idx_map        = (int*)(ws + 0);                       // 2,359,296
    unsigned short* w1t = (unsigned short*)(ws + 2359296);      // 32,768
    unsigned short* w2t = (unsigned short*)(ws + 2392064);      // 73,728
    unsigned short* w3t = (unsigned short*)(ws + 2465792);      // 32,768
    unsigned short* out1= (unsigned short*)(ws + 2498560);      // 25,600,000
    unsigned short* out2= (unsigned short*)(ws + 28098560);     // 25,600,000
    unsigned short* zrow= (unsigned short*)(ws + 53698560);     // 128 zero bytes
    // total: 53,698,688 bytes

    hipMemsetAsync(idx_map, 0xFF, (size_t)HH * WW * 4, stream);
    hipMemsetAsync(zrow, 0x00, 128, stream);
    k_scatter<<<(NN + 255) / 256, 256, 0, stream>>>(coords, idx_map);
    k_prepw<<<64, 256, 0, stream>>>(w1, w2, w3, w1t, w2t, w3t);
    k_gemm1<<<(NN + 127) / 128, 256, 0, stream>>>(feats, w1t, s1, b1, out1);
    k_conv<<<(NN + 127) / 128, 256, 0, stream>>>(out1, w2t, coords, idx_map, s2, b2, zrow, out2);
    k_gemm3<<<(NN + 127) / 128, 256, 0, stream>>>(out2, w3t, s3, b3, feats, out);
}

// Round 2
// 535.705 us; speedup vs baseline: 1.0866x; 1.0866x over previous
//
#include <hip/hip_runtime.h>
#include <hip/hip_bf16.h>
#include <stdint.h>

#define HH 768
#define WW 768
#define NN 200000
#define CI 256
#define CB 64

typedef __attribute__((ext_vector_type(8))) __bf16 bf16x8;
typedef __attribute__((ext_vector_type(4))) float f32x4;
typedef __attribute__((ext_vector_type(4))) unsigned short u16x4;

__device__ inline unsigned short f2bf(float f) {
    union { float f; unsigned int i; } v; v.f = f;
    unsigned int r = v.i + 0x7FFF + ((v.i >> 16) & 1);
    return (unsigned short)(r >> 16);
}
__device__ inline f32x4 mfma16(bf16x8 a, bf16x8 b, f32x4 c) {
    return __builtin_amdgcn_mfma_f32_16x16x32_bf16(a, b, c, 0, 0, 0);
}
__device__ inline bf16x8 ldfrag(const unsigned short* p) {
    return *(const bf16x8*)p;
}
__device__ inline bf16x8 ldfrag_f32(const float* p) {
    float4 f0 = *(const float4*)(p);
    float4 f1 = *(const float4*)(p + 4);
    bf16x8 a;
    a[0] = (__bf16)f0.x; a[1] = (__bf16)f0.y; a[2] = (__bf16)f0.z; a[3] = (__bf16)f0.w;
    a[4] = (__bf16)f1.x; a[5] = (__bf16)f1.y; a[6] = (__bf16)f1.z; a[7] = (__bf16)f1.w;
    return a;
}

// ---------------- prep kernels ----------------

__global__ void k_scatter(const int* __restrict__ coords, int* __restrict__ idx_map) {
    int i = blockIdx.x * 256 + threadIdx.x;
    if (i < NN) idx_map[coords[i]] = i;
}

__global__ void k_prepw(const float* __restrict__ w1,
                        const float* __restrict__ w2,
                        const float* __restrict__ w3,
                        unsigned short* __restrict__ w1t,
                        unsigned short* __restrict__ w2t,
                        unsigned short* __restrict__ w3t) {
    int tid = blockIdx.x * 256 + threadIdx.x;
    int stride = gridDim.x * 256;
    for (int i = tid; i < CI * CB; i += stride) {      // w1 [256][64] -> w1t [64][256]
        int k = i / CB, n = i % CB;
        w1t[n * CI + k] = f2bf(w1[i]);
    }
    for (int i = tid; i < 9 * CB * CB; i += stride) {  // w2 [9][64][64] -> per-tap [n][k]
        int t = i / (CB * CB), rem = i % (CB * CB);
        int k = rem / CB, n = rem % CB;
        w2t[t * CB * CB + n * CB + k] = f2bf(w2[i]);
    }
    for (int i = tid; i < CB * CI; i += stride) {      // w3 [64][256] -> w3t [256][64]
        int k = i / CI, n = i % CI;
        w3t[n * CB + k] = f2bf(w3[i]);
    }
}

// ---------------- stage 1: out1 = relu((feats @ w1)*s1 + b1), N x 64 ----------------

__global__ __launch_bounds__(256, 4) void k_gemm1(const float* __restrict__ feats,
                                                  const unsigned short* __restrict__ w1t,
                                                  const float* __restrict__ s1,
                                                  const float* __restrict__ b1,
                                                  unsigned short* __restrict__ out1) {
    const int wave = threadIdx.x >> 6;
    const int lane = threadIdx.x & 63;
    const int m = lane & 15;
    const int quad = lane >> 4;
    const int row0 = blockIdx.x * 128 + wave * 32;
    if (row0 >= NN) return;

    f32x4 acc[2][4];   // [rt][ct]
#pragma unroll
    for (int rt = 0; rt < 2; ++rt)
#pragma unroll
        for (int ct = 0; ct < 4; ++ct) acc[rt][ct] = (f32x4){0.f, 0.f, 0.f, 0.f};

#pragma unroll
    for (int ks = 0; ks < 8; ++ks) {
        bf16x8 f[2];
#pragma unroll
        for (int rt = 0; rt < 2; ++rt)
            f[rt] = ldfrag_f32(feats + (size_t)(row0 + rt * 16 + m) * CI + quad * 8 + ks * 32);
#pragma unroll
        for (int ct = 0; ct < 4; ++ct) {
            bf16x8 b = ldfrag(w1t + (ct * 16 + m) * CI + quad * 8 + ks * 32);
#pragma unroll
            for (int rt = 0; rt < 2; ++rt)
                acc[rt][ct] = mfma16(b, f[rt], acc[rt][ct]);   // swapped: C^T frag
        }
    }

#pragma unroll
    for (int rt = 0; rt < 2; ++rt)
#pragma unroll
        for (int ct = 0; ct < 4; ++ct) {
            int row = row0 + rt * 16 + m;
            int c0 = ct * 16 + quad * 4;
            float4 sc = *(const float4*)(s1 + c0);
            float4 bi = *(const float4*)(b1 + c0);
            float v0 = acc[rt][ct][0] * sc.x + bi.x;
            float v1 = acc[rt][ct][1] * sc.y + bi.y;
            float v2 = acc[rt][ct][2] * sc.z + bi.z;
            float v3 = acc[rt][ct][3] * sc.w + bi.w;
            u16x4 o;
            o.x = f2bf(v0 > 0.f ? v0 : 0.f);
            o.y = f2bf(v1 > 0.f ? v1 : 0.f);
            o.z = f2bf(v2 > 0.f ? v2 : 0.f);
            o.w = f2bf(v3 > 0.f ? v3 : 0.f);
            *(u16x4*)(out1 + (size_t)row * CB + c0) = o;
        }
}

// ---------------- fused stage 2+3: conv3x3+bn2+relu -> (x @ w3)*s3+b3+feats -> relu ----
// block = 128 rows, wave = 32 rows. Conv acc is re-laid out for the second MFMA via a
// wave-local LDS transpose (padded stride 68 to spread banks). Residual feats loads are
// double-buffered one 64-col chunk ahead (chunk 0 issued at kernel entry) so the four
// output chunks overlap instead of serializing.

__global__ __launch_bounds__(256, 2) void k_conv3(const unsigned short* __restrict__ out1,
                                                  const unsigned short* __restrict__ w2t,
                                                  const unsigned short* __restrict__ w3t,
                                                  const int* __restrict__ coords,
                                                  const int* __restrict__ idx_map,
                                                  const float* __restrict__ s2,
                                                  const float* __restrict__ b2,
                                                  const float* __restrict__ s3,
                                                  const float* __restrict__ b3,
                                                  const unsigned short* __restrict__ zrow,
                                                  const float* __restrict__ feats,
                                                  float* __restrict__ out) {
    __shared__ int s_nbr[128 * 9];
    __shared__ unsigned short s_x[4][32][68];   // per-wave transpose buffer, pad 64->68

    const int tid = threadIdx.x;
    const int wave = tid >> 6;
    const int lane = tid & 63;
    const int m = lane & 15;
    const int quad = lane >> 4;
    const int row0 = blockIdx.x * 128 + wave * 32;
    const bool live = (row0 < NN);

    // ---- prefetch residual chunk 0 (independent of everything) ----
    float4 fr[2][2][4];   // [parity][rt][ct] — indices static after unroll
    if (live) {
#pragma unroll
        for (int rt = 0; rt < 2; ++rt)
#pragma unroll
            for (int ct = 0; ct < 4; ++ct)
                fr[0][rt][ct] = *(const float4*)(feats + (size_t)(row0 + rt * 16 + m) * CI
                                                 + ct * 16 + quad * 4);
    }

    // ---- neighbor table ----
    if (tid < 128) {
        int grow = blockIdx.x * 128 + tid;
        if (grow < NN) {
            int c = coords[grow];
            int y = c / WW, x = c - y * WW;
#pragma unroll
            for (int t = 0; t < 9; ++t) {
                int dy = t / 3 - 1, dx = t % 3 - 1;
                int ny = y + dy, nx = x + dx;
                int r = -1;
                if (ny >= 0 && ny < HH && nx >= 0 && nx < WW) r = idx_map[ny * WW + nx];
                s_nbr[tid * 9 + t] = r;
            }
        } else {
#pragma unroll
            for (int t = 0; t < 9; ++t) s_nbr[tid * 9 + t] = -1;
        }
    }
    __syncthreads();
    if (!live) return;

    // ---- conv 3x3 (gathered), swapped-operand MFMA ----
    f32x4 acc[2][4];   // [rt][ct]
#pragma unroll
    for (int rt = 0; rt < 2; ++rt)
#pragma unroll
        for (int ct = 0; ct < 4; ++ct) acc[rt][ct] = (f32x4){0.f, 0.f, 0.f, 0.f};

#pragma unroll
    for (int t = 0; t < 9; ++t) {
        bf16x8 a[2][2];
#pragma unroll
        for (int rt = 0; rt < 2; ++rt) {
            int r = s_nbr[(wave * 32 + rt * 16 + m) * 9 + t];
            const unsigned short* base = (r >= 0) ? (out1 + (size_t)r * CB) : zrow;
            a[rt][0] = ldfrag(base + quad * 8);
            a[rt][1] = ldfrag(base + quad * 8 + 32);
        }
#pragma unroll
        for (int ks = 0; ks < 2; ++ks)
#pragma unroll
            for (int ct = 0; ct < 4; ++ct) {
                bf16x8 b = ldfrag(w2t + t * CB * CB + (ct * 16 + m) * CB + quad * 8 + ks * 32);
#pragma unroll
                for (int rt = 0; rt < 2; ++rt)
                    acc[rt][ct] = mfma16(b, a[rt][ks], acc[rt][ct]);
            }
    }

    // ---- bn2 + relu -> bf16 -> wave-local LDS transpose ----
#pragma unroll
    for (int rt = 0; rt < 2; ++rt)
#pragma unroll
        for (int ct = 0; ct < 4; ++ct) {
            int c0 = ct * 16 + quad * 4;
            float4 sc = *(const float4*)(s2 + c0);
            float4 bi = *(const float4*)(b2 + c0);
            float v0 = acc[rt][ct][0] * sc.x + bi.x;
            float v1 = acc[rt][ct][1] * sc.y + bi.y;
            float v2 = acc[rt][ct][2] * sc.z + bi.z;
            float v3 = acc[rt][ct][3] * sc.w + bi.w;
            u16x4 o;
            o.x = f2bf(v0 > 0.f ? v0 : 0.f);
            o.y = f2bf(v1 > 0.f ? v1 : 0.f);
            o.z = f2bf(v2 > 0.f ? v2 : 0.f);
            o.w = f2bf(v3 > 0.f ? v3 : 0.f);
            *(u16x4*)&s_x[wave][rt * 16 + m][c0] = o;
        }

    // read back in gemm3 A-fragment layout (wave-local: compiler inserts lgkmcnt)
    bf16x8 a3[2][2];
#pragma unroll
    for (int rt = 0; rt < 2; ++rt)
#pragma unroll
        for (int ks = 0; ks < 2; ++ks)
            a3[rt][ks] = ldfrag(&s_x[wave][rt * 16 + m][ks * 32 + quad * 8]);

    // ---- gemm3: 4 chunks of 64 cols, residual prefetched one chunk ahead ----
#pragma unroll
    for (int cc = 0; cc < 4; ++cc) {
        // prefetch chunk cc+1 residual
        if (cc < 3) {
#pragma unroll
            for (int rt = 0; rt < 2; ++rt)
#pragma unroll
                for (int ct = 0; ct < 4; ++ct)
                    fr[(cc + 1) & 1][rt][ct] =
                        *(const float4*)(feats + (size_t)(row0 + rt * 16 + m) * CI
                                         + (cc + 1) * 64 + ct * 16 + quad * 4);
        }

        const int cbase = cc * 64;
        f32x4 acc3[2][4];
#pragma unroll
        for (int rt = 0; rt < 2; ++rt)
#pragma unroll
            for (int ct = 0; ct < 4; ++ct) acc3[rt][ct] = (f32x4){0.f, 0.f, 0.f, 0.f};

#pragma unroll
        for (int ks = 0; ks < 2; ++ks)
#pragma unroll
            for (int ct = 0; ct < 4; ++ct) {
                bf16x8 b = ldfrag(w3t + (cbase + ct * 16 + m) * CB + quad * 8 + ks * 32);
#pragma unroll
                for (int rt = 0; rt < 2; ++rt)
                    acc3[rt][ct] = mfma16(b, a3[rt][ks], acc3[rt][ct]);
            }

#pragma unroll
        for (int rt = 0; rt < 2; ++rt)
#pragma unroll
            for (int ct = 0; ct < 4; ++ct) {
                int row = row0 + rt * 16 + m;
                int c0 = cbase + ct * 16 + quad * 4;
                float4 sc = *(const float4*)(s3 + c0);
                float4 bi = *(const float4*)(b3 + c0);
                float4 f = fr[cc & 1][rt][ct];
                float4 v;
                v.x = acc3[rt][ct][0] * sc.x + bi.x + f.x;
                v.y = acc3[rt][ct][1] * sc.y + bi.y + f.y;
                v.z = acc3[rt][ct][2] * sc.z + bi.z + f.z;
                v.w = acc3[rt][ct][3] * sc.w + bi.w + f.w;
                v.x = v.x > 0.f ? v.x : 0.f;
                v.y = v.y > 0.f ? v.y : 0.f;
                v.z = v.z > 0.f ? v.z : 0.f;
                v.w = v.w > 0.f ? v.w : 0.f;
                *(float4*)(out + (size_t)row * CI + c0) = v;
            }
    }
}

// ---------------- launch ----------------

extern "C" void kernel_launch(void* const* d_in, const int* in_sizes, int n_in,
                              void* d_out, int out_size, void* d_ws, size_t ws_size,
                              hipStream_t stream) {
    const float* feats = (const float*)d_in[0];
    const int* coords = (const int*)d_in[1];
    const float* w1 = (const float*)d_in[2];
    const float* w2 = (const float*)d_in[3];
    const float* w3 = (const float*)d_in[4];
    const float* s1 = (const float*)d_in[5];
    const float* b1 = (const float*)d_in[6];
    const float* s2 = (const float*)d_in[7];
    const float* b2 = (const float*)d_in[8];
    const float* s3 = (const float*)d_in[9];
    const float* b3 = (const float*)d_in[10];
    float* out = (float*)d_out;

    char* ws = (char*)d_ws;
    int* idx_map        = (int*)(ws + 0);                       // 2,359,296
    unsigned short* w1t = (unsigned short*)(ws + 2359296);      // 32,768
    unsigned short* w2t = (unsigned short*)(ws + 2392064);      // 73,728
    unsigned short* w3t = (unsigned short*)(ws + 2465792);      // 32,768
    unsigned short* out1= (unsigned short*)(ws + 2498560);      // 25,600,000
    // region formerly used by out2 (25.6 MB) now unused
    unsigned short* zrow= (unsigned short*)(ws + 53698560);     // 128 zero bytes
    // total: 53,698,688 bytes

    hipMemsetAsync(idx_map, 0xFF, (size_t)HH * WW * 4, stream);
    hipMemsetAsync(zrow, 0x00, 128, stream);
    k_scatter<<<(NN + 255) / 256, 256, 0, stream>>>(coords, idx_map);
    k_prepw<<<64, 256, 0, stream>>>(w1, w2, w3, w1t, w2t, w3t);
    k_gemm1<<<(NN + 127) / 128, 256, 0, stream>>>(feats, w1t, s1, b1, out1);
    k_conv3<<<(NN + 127) / 128, 256, 0, stream>>>(out1, w2t, w3t, coords, idx_map,
                                                  s2, b2, s3, b3, zrow, feats, out);
}